// Round 13
// baseline (325.048 us; speedup 1.0000x reference)
//
#include <hip/hip_runtime.h>

#define T_STEPS 512
#define INPUT   13
#define HIDDEN  64
#define MB      16    // full MFMA M-tile, grid 256 = 1 block/CU
#define CS      8     // timesteps per x-chunk
#define NCHUNK  (T_STEPS / CS)
#define NTHREADS 512  // 8 waves: gate-type = w>>1, cell-group pair = (w&1)*2
#define LOG2E   1.44269504088896f

typedef __attribute__((ext_vector_type(8))) _Float16 f16x8;  // MFMA A/B frag
typedef __attribute__((ext_vector_type(4)))  float   f32x4;  // MFMA C/D frag

__device__ __forceinline__ float exp2_f(float x) { return __builtin_amdgcn_exp2f(x); }
__device__ __forceinline__ float rcp_f(float x)  { return __builtin_amdgcn_rcpf(x); }
__device__ __forceinline__ float sigmoid_f(float x) {           // epilogue only
    return rcp_f(1.0f + exp2_f(-LOG2E * x));
}

// R12 post-mortem: wall 1125 cyc/step/SIMD = issue (MFMA 192 + VALU ~595) +
// ~330 serial-phase latency no one can hide at 1 wave/SIMD. R8 showed waves
// bought with DEAD ROWS lose; R13 buys a 2nd wave/SIMD with ZERO extra work:
// 8 waves x 2 gate-tiles (6 MFMA/wave/step), preacts exchanged via 16KB
// gl[gt][row][cell] (2-way banks = free), cell update spread over all 512
// lanes (2 cells/lane -> 16 trans, half of R12). Per-CU issue unchanged;
// serial phases of the 2 waves/SIMD interleave. Numerics IDENTICAL to R12
// (same f16 h, same algebra) -> absmax must stay exactly 0.00390625.
__global__ __launch_bounds__(NTHREADS)
void lstm_mfma_kernel(const float* __restrict__ x,
                      const float* __restrict__ W_ih,
                      const float* __restrict__ W_hh,
                      const float* __restrict__ b_ih,
                      const float* __restrict__ b_hh,
                      const float* __restrict__ W_fc,
                      const float* __restrict__ b_fc,
                      float* __restrict__ out)
{
    __shared__ _Float16 hA[2][MB][HIDDEN];     // 4 KB, XOR-swizzled (R12 layout)
    __shared__ _Float16 xA[2][CS][MB][32];     // 16 KB (R12 layout)
    __shared__ float    gl[4][MB][HIDDEN];     // 16 KB pre-activation exchange
    __shared__ float    hf[MB][HIDDEN];        // 4 KB epilogue

    const int tid = threadIdx.x;
    const int w   = tid >> 6;        // wave 0..7
    const int l   = tid & 63;
    const int lr  = l & 15;
    const int lg  = l >> 4;
    const int gt  = w >> 1;          // this wave's gate type (0=i,1=f,2=g,3=o)
    const int cgb = (w & 1) * 2;     // first of two owned cell-groups
    const int row0 = blockIdx.x * MB;

    // ---- resident weight B-frags: 2 tiles x {x, h0, h1} ----
    const float scl = (gt == 2) ? (2.0f * LOG2E) : (-LOG2E);
    f16x8 Bh[2][2], Bx[2];
    f32x4 biasv[2];
    #pragma unroll
    for (int t = 0; t < 2; ++t) {
        const int gate = gt * 64 + (cgb + t) * 16 + lr;
        const float b  = scl * (b_ih[gate] + b_hh[gate]);
        biasv[t] = (f32x4){b, b, b, b};
        #pragma unroll
        for (int kf = 0; kf < 2; ++kf)
            #pragma unroll
            for (int j = 0; j < 8; ++j)
                Bh[t][kf][j] = (_Float16)(scl * W_hh[gate * HIDDEN + kf * 32 + lg * 8 + j]);
        #pragma unroll
        for (int j = 0; j < 8; ++j) {
            const int k = lg * 8 + j;
            Bx[t][j] = (_Float16)((k < INPUT) ? scl * W_ih[gate * INPUT + k] : 0.0f);
        }
    }

    // ---- precomputed LDS pointers ----
    const f16x8* phr[2][2];          // h A-frag reads (R12 pattern)
    #pragma unroll
    for (int hb = 0; hb < 2; ++hb)
        #pragma unroll
        for (int kf = 0; kf < 2; ++kf) {
            const int slot = (kf * 4 + lg) ^ (lr & 7);
            phr[hb][kf] = (const f16x8*)((const char*)&hA[hb][lr][0] + slot * 16);
        }
    const int slx = lg ^ (lr & 3);   // x A-frag reads
    const f16x8* px = (const f16x8*)((const char*)&xA[0][0][lr][0] + slx * 16);

    // gl writes: tile t -> rows lg*4+r (imm offset r*HIDDEN), col (cgb+t)*16+lr
    float* pglw[2];
    #pragma unroll
    for (int t = 0; t < 2; ++t)
        pglw[t] = &gl[gt][lg * 4][(cgb + t) * 16 + lr];

    // cell-update ownership: units (2tid, 2tid+1) -> row = tid>>5, cells c0,c0+1
    const int urow = tid >> 5;
    const int c0   = (2 * tid) & 63;           // even
    const float* pglr = &gl[0][urow][c0];      // gt stride = MB*HIDDEN floats
    // h writes: cells c0, c0+1 land at adjacent swizzled slots kp0, kp0+1
    const int kp0 = (c0 & 7) | (((c0 >> 3) ^ (urow & 7)) << 3);
    _Float16* pwh[2];
    #pragma unroll
    for (int hb = 0; hb < 2; ++hb)
        pwh[hb] = &hA[hb][urow][kp0];

    // ---- zero LDS (h0 = 0; x pad slots stay 0 forever) ----
    for (int i = tid; i < 2 * MB * HIDDEN; i += NTHREADS)
        ((unsigned short*)hA)[i] = 0;
    for (int i = tid; i < 2 * CS * MB * 32; i += NTHREADS)
        ((unsigned short*)xA)[i] = 0;

    float c[2]    = {0.f, 0.f};
    float hreg[2] = {0.f, 0.f};

    // ---- x chunk loader: 2048 slots / 512 threads = 4 each ----
    float stg[4];
    auto load_chunk = [&](int ch) {
        #pragma unroll
        for (int s = 0; s < 4; ++s) {
            const int idx = tid + s * NTHREADS;  // 0..2047
            const int i   = idx & 15;
            const int tt  = (idx >> 4) & 7;
            const int r   = idx >> 7;            // 0..15
            float v = 0.0f;
            if (i < INPUT)
                v = x[(size_t)(row0 + r) * (T_STEPS * INPUT)
                      + (size_t)(ch * CS + tt) * INPUT + i];
            stg[s] = v;
        }
    };
    auto store_chunk = [&](int buf) {
        #pragma unroll
        for (int s = 0; s < 4; ++s) {
            const int idx = tid + s * NTHREADS;
            const int i   = idx & 15;
            const int tt  = (idx >> 4) & 7;
            const int r   = idx >> 7;
            const int kp  = (i & 7) | (((i >> 3) ^ (r & 3)) << 3);
            xA[buf][tt][r][kp] = (_Float16)stg[s];
        }
    };

    load_chunk(0);
    __syncthreads();          // zero-init visible
    store_chunk(0);
    __syncthreads();

    for (int ch = 0; ch < NCHUNK; ++ch) {
        const int cur = ch & 1;
        const f16x8* pxc = px + cur * 512;
        if (ch + 1 < NCHUNK)
            load_chunk(ch + 1);          // global loads in flight over 8 steps

        #pragma unroll
        for (int tt = 0; tt < CS; ++tt) {
            const int hb  = tt & 1;      // read parity (CS even -> consistent)
            const int hbw = hb ^ 1;      // write parity

            // ---- A-frag reads (shared across both tiles) ----
            const f16x8 ax  = pxc[tt * 64];
            const f16x8 ah0 = phr[hb][0][0];
            const f16x8 ah1 = phr[hb][1][0];

            // ---- 2 tiles x 3-deep MFMA chain (bias as C-in) ----
            f32x4 a0 = biasv[0], a1 = biasv[1];
            a0 = __builtin_amdgcn_mfma_f32_16x16x32_f16(ax,  Bx[0],    a0, 0, 0, 0);
            a1 = __builtin_amdgcn_mfma_f32_16x16x32_f16(ax,  Bx[1],    a1, 0, 0, 0);
            a0 = __builtin_amdgcn_mfma_f32_16x16x32_f16(ah0, Bh[0][0], a0, 0, 0, 0);
            a1 = __builtin_amdgcn_mfma_f32_16x16x32_f16(ah0, Bh[1][0], a1, 0, 0, 0);
            a0 = __builtin_amdgcn_mfma_f32_16x16x32_f16(ah1, Bh[0][1], a0, 0, 0, 0);
            a1 = __builtin_amdgcn_mfma_f32_16x16x32_f16(ah1, Bh[1][1], a1, 0, 0, 0);

            // ---- publish pre-activations (b32, imm offsets, 2-way banks) ----
            #pragma unroll
            for (int r = 0; r < 4; ++r) {
                pglw[0][r * HIDDEN] = a0[r];
                pglw[1][r * HIDDEN] = a1[r];
            }
            __syncthreads();

            // ---- cell update: 2 cells/lane, combined-rcp algebra ----
            #pragma unroll
            for (int u = 0; u < 2; ++u) {
                const float A = exp2_f(pglr[u]);                       // i
                const float F = exp2_f(pglr[u + 1 * MB * HIDDEN]);     // f
                const float B = exp2_f(pglr[u + 2 * MB * HIDDEN]);     // g
                const float O = exp2_f(pglr[u + 3 * MB * HIDDEN]);     // o
                const float ig = (B - 1.0f) * rcp_f((1.0f + A) * (1.0f + B));
                const float cn = fmaf(c[u], rcp_f(1.0f + F), ig);
                c[u] = cn;
                const float T = exp2_f((2.0f * LOG2E) * cn);
                const float h = (T - 1.0f) * rcp_f((1.0f + O) * (1.0f + T));
                hreg[u] = h;
                pwh[hbw][u] = (_Float16)h;      // adjacent swizzled slots
            }

            // fold chunk staging into the last step (no extra barrier)
            if (tt == CS - 1 && ch + 1 < NCHUNK)
                store_chunk(1 - cur);

            __syncthreads();
        }
    }

    // ---- epilogue: out[row] = sigmoid(h_T . W_fc + b_fc) ----
    *(float2*)&hf[urow][c0] = make_float2(hreg[0], hreg[1]);
    __syncthreads();
    if (tid < MB) {
        float a = b_fc[0];
        #pragma unroll
        for (int j = 0; j < HIDDEN; ++j)
            a = fmaf(hf[tid][j], W_fc[j], a);
        out[row0 + tid] = sigmoid_f(a);
    }
}

extern "C" void kernel_launch(void* const* d_in, const int* in_sizes, int n_in,
                              void* d_out, int out_size, void* d_ws, size_t ws_size,
                              hipStream_t stream) {
    const float* x    = (const float*)d_in[0];
    const float* W_ih = (const float*)d_in[1];
    const float* W_hh = (const float*)d_in[2];
    const float* b_ih = (const float*)d_in[3];
    const float* b_hh = (const float*)d_in[4];
    const float* W_fc = (const float*)d_in[5];
    const float* b_fc = (const float*)d_in[6];
    float* out = (float*)d_out;

    const int B = 4096;
    dim3 grid(B / MB), block(NTHREADS);
    lstm_mfma_kernel<<<grid, block, 0, stream>>>(x, W_ih, W_hh, b_ih, b_hh,
                                                 W_fc, b_fc, out);
}